// Round 3
// baseline (247.471 us; speedup 1.0000x reference)
//
#include <hip/hip_runtime.h>

#define N_NODES_C 50000
#define N_EDGES_C 800000
#define IN_FEATS_C 128
#define HEADS_C 8
#define HD_C 256            // HEADS * OUT_FEATS
#define NEG_SLOPE_C 0.2f
#define SCAN_NBLK 49        // ceil(50000/1024)
#define LDT 136             // LDS row stride in shorts (272 B = 17*16, 16B-aligned)

#define GEMM_BLOCKS 782     // ceil(50000/128) * 2 channel tiles
#define DEG_BLOCKS 242
#define K1_GRID (GEMM_BLOCKS + DEG_BLOCKS)   // 1024

typedef __attribute__((ext_vector_type(8))) short bf16x8;
typedef __attribute__((ext_vector_type(4))) float floatx4;
typedef __attribute__((ext_vector_type(4))) unsigned int uintx4;

__device__ inline unsigned short f2bf(float f) {
  unsigned int u = __float_as_uint(f);
  unsigned int r = (u + 0x7FFFu + ((u >> 16) & 1u)) >> 16;   // RNE
  return (unsigned short)r;
}
__device__ inline float bf2f(unsigned short s) {
  unsigned int u = ((unsigned int)s) << 16;
  return __uint_as_float(u);
}

// 49-entry exclusive scan of bsum into sboff[64] (first wave only, then barrier)
__device__ inline void boff_scan(const int* __restrict__ bsum, int* sboff) {
  int t = threadIdx.x;
  if (t < 64) {
    int own = (t < SCAN_NBLK) ? bsum[t] : 0;
    int v = own;
#pragma unroll
    for (int off = 1; off < 64; off <<= 1) {
      int u = __shfl_up(v, off);
      if (t >= off) v += u;
    }
    sboff[t] = v - own;   // exclusive
  }
  __syncthreads();
}

// ============ K1: deg+rank histogram (0..241) || MFMA gemm + fused el/er ============
__global__ __launch_bounds__(256) void front_kernel(
    const float* __restrict__ feat, const float* __restrict__ W,
    const float* __restrict__ attn_l, const float* __restrict__ attn_r,
    const int* __restrict__ dst,
    unsigned short* __restrict__ feat_hd_bf,
    float* __restrict__ el, float* __restrict__ er,
    int* __restrict__ deg, int* __restrict__ rank) {
  __shared__ __align__(16) unsigned short sA[128 * LDT];   // 34816 B; reused as sOut
  __shared__ float sAttnL[128];
  __shared__ float sAttnR[128];
  const int bid = blockIdx.x;
  const int t = threadIdx.x;

  if (bid < DEG_BLOCKS) {
    // ---- degree histogram + rank capture, 8 atomics in flight ----
    for (int e0 = (bid * 256 + t) * 8; e0 < N_EDGES_C; e0 += DEG_BLOCKS * 2048) {
      int4 da = *(const int4*)&dst[e0];
      int4 db = *(const int4*)&dst[e0 + 4];
      int r0 = atomicAdd(&deg[da.x], 1);
      int r1 = atomicAdd(&deg[da.y], 1);
      int r2 = atomicAdd(&deg[da.z], 1);
      int r3 = atomicAdd(&deg[da.w], 1);
      int r4 = atomicAdd(&deg[db.x], 1);
      int r5 = atomicAdd(&deg[db.y], 1);
      int r6 = atomicAdd(&deg[db.z], 1);
      int r7 = atomicAdd(&deg[db.w], 1);
      *(int4*)&rank[e0]     = make_int4(r0, r1, r2, r3);
      *(int4*)&rank[e0 + 4] = make_int4(r4, r5, r6, r7);
    }
    return;
  }

  const int gb = bid - DEG_BLOCKS;
  const int nt = gb & 1;               // channel tile (heads nt*4 .. nt*4+3)
  const int mt = gb >> 1;
  const int m0 = mt * 128;
  const int n0 = nt * 128;

  if (t < 128) {
    sAttnL[t] = attn_l[n0 + t];
    sAttnR[t] = attn_r[n0 + t];
  }
  // stage A: 128 rows x 32 float4 of feat -> bf16 (nt loads: feat is stream-once here)
#pragma unroll
  for (int i = 0; i < 16; ++i) {
    int idx = t + i * 256;
    int row = idx >> 5;
    int c4 = idx & 31;
    int gn = m0 + row;
    floatx4 v = (floatx4){0.f, 0.f, 0.f, 0.f};
    if (gn < N_NODES_C)
      v = __builtin_nontemporal_load(
          (const floatx4*)&feat[(size_t)gn * IN_FEATS_C + c4 * 4]);
    ushort4 b;
    b.x = f2bf(v[0]); b.y = f2bf(v[1]); b.z = f2bf(v[2]); b.w = f2bf(v[3]);
    *(ushort4*)&sA[row * LDT + c4 * 4] = b;
  }
  __syncthreads();

  const int wid = t >> 6;
  const int lane = t & 63;
  const int quad = lane >> 4;
  const int l16 = lane & 15;
  const int wm = (wid & 1) * 64;
  const int wn = (wid >> 1) * 64;

  floatx4 acc[4][4];
#pragma unroll
  for (int i = 0; i < 4; ++i)
#pragma unroll
    for (int j = 0; j < 4; ++j) acc[i][j] = (floatx4){0.f, 0.f, 0.f, 0.f};

#pragma unroll
  for (int ks = 0; ks < 4; ++ks) {
    int k0 = ks * 32 + quad * 8;
    bf16x8 bfv[4];
#pragma unroll
    for (int n2 = 0; n2 < 4; ++n2) {
      const float* wp = &W[(size_t)(n0 + wn + n2 * 16 + l16) * IN_FEATS_C + k0];
      float4 w0 = *(const float4*)wp;
      float4 w1 = *(const float4*)(wp + 4);
      bf16x8 b;
      b[0] = (short)f2bf(w0.x); b[1] = (short)f2bf(w0.y);
      b[2] = (short)f2bf(w0.z); b[3] = (short)f2bf(w0.w);
      b[4] = (short)f2bf(w1.x); b[5] = (short)f2bf(w1.y);
      b[6] = (short)f2bf(w1.z); b[7] = (short)f2bf(w1.w);
      bfv[n2] = b;
    }
    bf16x8 af[4];
#pragma unroll
    for (int m2 = 0; m2 < 4; ++m2)
      af[m2] = *(const bf16x8*)&sA[(wm + m2 * 16 + l16) * LDT + k0];
#pragma unroll
    for (int m2 = 0; m2 < 4; ++m2)
#pragma unroll
      for (int n2 = 0; n2 < 4; ++n2)
        acc[m2][n2] = __builtin_amdgcn_mfma_f32_16x16x32_bf16(
            af[m2], bfv[n2], acc[m2][n2], 0, 0, 0);
  }
  __syncthreads();

  // epilogue: D layout col=l16, row=quad*4+reg -> repack via LDS
#pragma unroll
  for (int m2 = 0; m2 < 4; ++m2)
#pragma unroll
    for (int n2 = 0; n2 < 4; ++n2)
#pragma unroll
      for (int r = 0; r < 4; ++r) {
        int row = wm + m2 * 16 + quad * 4 + r;
        int col = wn + n2 * 16 + l16;
        sA[row * LDT + col] = f2bf(acc[m2][n2][r]);
      }
  __syncthreads();

  // coalesced store of the bf16 tile (nt: 25.6 MB stream, read much later by agg)
#pragma unroll
  for (int i = 0; i < 8; ++i) {
    int idx = t + i * 256;
    int row = idx >> 4;
    int ch = idx & 15;
    int gn = m0 + row;
    if (gn < N_NODES_C) {
      uintx4 v = *(const uintx4*)&sA[row * LDT + ch * 8];
      __builtin_nontemporal_store(
          v, (uintx4*)&feat_hd_bf[(size_t)gn * HD_C + n0 + ch * 8]);
    }
  }

  // fused el/er: thread t -> row t>>1, head-pair t&1 (2 heads x 32 ch)
  {
    int row = t >> 1;
    int hh = t & 1;
    int gn = m0 + row;
    if (gn < N_NODES_C) {
      const unsigned short* pr = &sA[row * LDT + hh * 64];
      const float* al = &sAttnL[hh * 64];
      const float* ar = &sAttnR[hh * 64];
      float el0 = 0.f, el1 = 0.f, er0 = 0.f, er1 = 0.f;
#pragma unroll
      for (int d = 0; d < 32; ++d) {
        float v0 = bf2f(pr[d]);
        float v1 = bf2f(pr[32 + d]);
        el0 = fmaf(v0, al[d], el0);
        er0 = fmaf(v0, ar[d], er0);
        el1 = fmaf(v1, al[32 + d], el1);
        er1 = fmaf(v1, ar[32 + d], er1);
      }
      int gh = nt * 4 + hh * 2;
      el[gn * HEADS_C + gh + 0] = el0;
      el[gn * HEADS_C + gh + 1] = el1;
      er[gn * HEADS_C + gh + 0] = er0;
      er[gn * HEADS_C + gh + 1] = er1;
    }
  }
}

// ============ scan1: also emits packed {row_start_incl, deg} int2 ============
__global__ __launch_bounds__(256) void scan1_kernel(
    const int* __restrict__ deg, int2* __restrict__ rsd,
    int* __restrict__ bsum) {
  __shared__ int s[256];
  int b = blockIdx.x, t = threadIdx.x;
  int i0 = b * 1024 + t * 4;
  int d0 = 0, d1 = 0, d2 = 0, d3 = 0;
  if (i0 + 4 <= N_NODES_C) {
    int4 d = *(const int4*)&deg[i0];
    d0 = d.x; d1 = d.y; d2 = d.z; d3 = d.w;
  } else {
    if (i0 + 0 < N_NODES_C) d0 = deg[i0 + 0];
    if (i0 + 1 < N_NODES_C) d1 = deg[i0 + 1];
    if (i0 + 2 < N_NODES_C) d2 = deg[i0 + 2];
    if (i0 + 3 < N_NODES_C) d3 = deg[i0 + 3];
  }
  int l1 = d0, l2 = l1 + d1, l3 = l2 + d2, l4 = l3 + d3;
  s[t] = l4;
  __syncthreads();
#pragma unroll
  for (int off = 1; off < 256; off <<= 1) {
    int add = (t >= off) ? s[t - off] : 0;
    __syncthreads();
    s[t] += add;
    __syncthreads();
  }
  int excl = s[t] - l4;
  if (i0 + 0 < N_NODES_C) rsd[i0 + 0] = make_int2(excl + l1, d0);
  if (i0 + 1 < N_NODES_C) rsd[i0 + 1] = make_int2(excl + l2, d1);
  if (i0 + 2 < N_NODES_C) rsd[i0 + 2] = make_int2(excl + l3, d2);
  if (i0 + 3 < N_NODES_C) rsd[i0 + 3] = make_int2(excl + l4, d3);
  if (t == 255) bsum[b] = s[255];
}

// ============ scatter: atomic-free, absolute CSR position from captured rank ============
__global__ __launch_bounds__(256) void scatter_kernel(
    const int* __restrict__ src, const int* __restrict__ dst,
    const int2* __restrict__ rsd, const int* __restrict__ bsum,
    const int* __restrict__ rank, int* __restrict__ csr_src) {
  __shared__ int sboff[64];
  boff_scan(bsum, sboff);
  int e = blockIdx.x * 256 + threadIdx.x;
  if (e >= N_EDGES_C) return;
  int d = dst[e];
  int2 v = rsd[d];                       // one 8B gather instead of two 4B
  int pos = v.x - v.y + sboff[d >> 10] + rank[e];
  csr_src[pos] = src[e];
}

// ============ aggregation over CSR: wave per dst node, 2-deep pipeline ============
// While computing block b, block b+1's feat gathers + el load are in flight
// and block b+2's index load is issued (T14 async-split, depth 2 -> ~16
// outstanding gathers/wave). Overrun blocks are masked (w=0); their clamped
// indices all hit the dg-1 row (L1-hot), so extra traffic is negligible.
__global__ __launch_bounds__(256) void agg_csr_kernel(
    const unsigned short* __restrict__ feat_hd_bf, const float* __restrict__ el,
    const float* __restrict__ er, const int2* __restrict__ rsd,
    const int* __restrict__ bsum, const int* __restrict__ csr_src,
    float* __restrict__ out) {
  __shared__ int sboff[64];
  boff_scan(bsum, sboff);
  int gid = blockIdx.x * 256 + threadIdx.x;
  int node = gid >> 6;
  int lane = threadIdx.x & 63;
  if (node >= N_NODES_C) return;
  int h = lane >> 3;
  int j8 = lane & 7;
  int hbase = lane & 56;               // h*8
  int c = lane * 4;
  float er_d = er[node * HEADS_C + h];
  int2 v = rsd[node];
  int dg = v.y;
  int rs = v.x - dg + sboff[node >> 10];
  float4 acc = make_float4(0.f, 0.f, 0.f, 0.f);
  float zsum = 0.f;

  int nb = (dg + 7) >> 3;              // number of 8-edge blocks (masked tail)
  if (nb > 0) {
    const int last = dg - 1;
    // prologue: block 0 fully loaded, block 1 index issued
    int idxA = csr_src[rs + min(j8, last)];
    float elA = el[idxA * HEADS_C + h];
    ushort4 fA[8];
#pragma unroll
    for (int j = 0; j < 8; ++j) {
      int sj = __shfl(idxA, j);
      fA[j] = *(const ushort4*)&feat_hd_bf[(size_t)sj * HD_C + c];
    }
    int idxB = csr_src[rs + min(8 + j8, last)];

    for (int b = 0; b < nb; b += 2) {
      // issue block b+1 loads (el + 8 feat gathers) and block b+2 index
      float elB = el[idxB * HEADS_C + h];
      ushort4 fB[8];
#pragma unroll
      for (int j = 0; j < 8; ++j) {
        int sj = __shfl(idxB, j);
        fB[j] = *(const ushort4*)&feat_hd_bf[(size_t)sj * HD_C + c];
      }
      int idxC = csr_src[rs + min((b + 2) * 8 + j8, last)];
      // ---- compute block b (fA/elA) ----
      {
        float x = elA + er_d;
        x = x > 0.f ? x : NEG_SLOPE_C * x;
        float wv = (b * 8 + j8 < dg) ? __expf(x) : 0.f;
        float wj[8];
#pragma unroll
        for (int j = 0; j < 8; ++j) wj[j] = __shfl(wv, hbase + j);
        zsum += ((wj[0] + wj[1]) + (wj[2] + wj[3])) +
                ((wj[4] + wj[5]) + (wj[6] + wj[7]));
#pragma unroll
        for (int j = 0; j < 8; ++j) {
          acc.x = fmaf(wj[j], bf2f(fA[j].x), acc.x);
          acc.y = fmaf(wj[j], bf2f(fA[j].y), acc.y);
          acc.z = fmaf(wj[j], bf2f(fA[j].z), acc.z);
          acc.w = fmaf(wj[j], bf2f(fA[j].w), acc.w);
        }
      }
      // issue block b+2 loads into the A slots, and block b+3 index
      float elA2 = el[idxC * HEADS_C + h];
#pragma unroll
      for (int j = 0; j < 8; ++j) {
        int sj = __shfl(idxC, j);
        fA[j] = *(const ushort4*)&feat_hd_bf[(size_t)sj * HD_C + c];
      }
      int idxD = csr_src[rs + min((b + 3) * 8 + j8, last)];
      // ---- compute block b+1 (fB/elB) ----
      {
        float x = elB + er_d;
        x = x > 0.f ? x : NEG_SLOPE_C * x;
        float wv = ((b + 1) * 8 + j8 < dg) ? __expf(x) : 0.f;
        float wj[8];
#pragma unroll
        for (int j = 0; j < 8; ++j) wj[j] = __shfl(wv, hbase + j);
        zsum += ((wj[0] + wj[1]) + (wj[2] + wj[3])) +
                ((wj[4] + wj[5]) + (wj[6] + wj[7]));
#pragma unroll
        for (int j = 0; j < 8; ++j) {
          acc.x = fmaf(wj[j], bf2f(fB[j].x), acc.x);
          acc.y = fmaf(wj[j], bf2f(fB[j].y), acc.y);
          acc.z = fmaf(wj[j], bf2f(fB[j].z), acc.z);
          acc.w = fmaf(wj[j], bf2f(fB[j].w), acc.w);
        }
      }
      idxA = idxC; elA = elA2; idxB = idxD;
    }
  }

  float inv = (dg > 0) ? 1.f / zsum : 0.f;
  floatx4 ov = (floatx4){acc.x * inv, acc.y * inv, acc.z * inv, acc.w * inv};
  // nt store: 51 MB of never-re-read output must not evict the feat_hd
  // working set from L2 (6.4 MB/XCD of write-allocate otherwise)
  __builtin_nontemporal_store(ov, (floatx4*)&out[(size_t)node * HD_C + c]);
}

extern "C" void kernel_launch(void* const* d_in, const int* in_sizes, int n_in,
                              void* d_out, int out_size, void* d_ws, size_t ws_size,
                              hipStream_t stream) {
  const float* feat   = (const float*)d_in[0];
  const float* W      = (const float*)d_in[1];
  const float* attn_l = (const float*)d_in[2];
  const float* attn_r = (const float*)d_in[3];
  const int* src      = (const int*)d_in[4];
  const int* dst      = (const int*)d_in[5];
  float* out = (float*)d_out;

  char* ws = (char*)d_ws;
  unsigned short* feat_hd_bf = (unsigned short*)ws;  ws += (size_t)N_NODES_C * HD_C * 2;     // 25.6 MB
  float* el      = (float*)ws;                       ws += (size_t)N_NODES_C * HEADS_C * 4;  // 1.6 MB
  float* er      = (float*)ws;                       ws += (size_t)N_NODES_C * HEADS_C * 4;  // 1.6 MB
  int* deg       = (int*)ws;                         ws += (size_t)N_NODES_C * 4;
  int2* rsd      = (int2*)ws;                        ws += (size_t)N_NODES_C * 8;            // packed {row_start, deg}
  int* bsum      = (int*)ws;                         ws += 64 * 4;
  int* csr_src   = (int*)ws;                         ws += (size_t)N_EDGES_C * 4;            // 3.2 MB
  int* rank      = (int*)ws;                         ws += (size_t)N_EDGES_C * 4;            // 3.2 MB

  hipMemsetAsync(deg, 0, (size_t)N_NODES_C * 4, stream);

  front_kernel<<<K1_GRID, 256, 0, stream>>>(feat, W, attn_l, attn_r, dst,
                                            feat_hd_bf, el, er, deg, rank);

  scan1_kernel<<<SCAN_NBLK, 256, 0, stream>>>(deg, rsd, bsum);

  scatter_kernel<<<(N_EDGES_C + 255) / 256, 256, 0, stream>>>(
      src, dst, rsd, bsum, rank, csr_src);

  agg_csr_kernel<<<(N_NODES_C + 3) / 4, 256, 0, stream>>>(
      feat_hd_bf, el, er, rsd, bsum, csr_src, out);
}

// Round 4
// 232.410 us; speedup vs baseline: 1.0648x; 1.0648x over previous
//
#include <hip/hip_runtime.h>

#define N_NODES_C 50000
#define N_EDGES_C 800000
#define IN_FEATS_C 128
#define HEADS_C 8
#define HD_C 256            // HEADS * OUT_FEATS
#define NEG_SLOPE_C 0.2f
#define SCAN_NBLK 49        // ceil(50000/1024)
#define LDT 136             // LDS row stride in shorts (272 B = 17*16, 16B-aligned)

#define GEMM_BLOCKS 782     // ceil(50000/128) * 2 channel tiles
#define DEG_BLOCKS 242
#define K1_GRID (GEMM_BLOCKS + DEG_BLOCKS)   // 1024
#define EMAX (N_EDGES_C - 1)

typedef __attribute__((ext_vector_type(8))) short bf16x8;
typedef __attribute__((ext_vector_type(4))) float floatx4;
typedef __attribute__((ext_vector_type(4))) unsigned int uintx4;

__device__ inline unsigned short f2bf(float f) {
  unsigned int u = __float_as_uint(f);
  unsigned int r = (u + 0x7FFFu + ((u >> 16) & 1u)) >> 16;   // RNE
  return (unsigned short)r;
}
__device__ inline float bf2f(unsigned short s) {
  unsigned int u = ((unsigned int)s) << 16;
  return __uint_as_float(u);
}

// 49-entry exclusive scan of bsum into sboff[64] (first wave only, then barrier)
__device__ inline void boff_scan(const int* __restrict__ bsum, int* sboff) {
  int t = threadIdx.x;
  if (t < 64) {
    int own = (t < SCAN_NBLK) ? bsum[t] : 0;
    int v = own;
#pragma unroll
    for (int off = 1; off < 64; off <<= 1) {
      int u = __shfl_up(v, off);
      if (t >= off) v += u;
    }
    sboff[t] = v - own;   // exclusive
  }
  __syncthreads();
}

// ============ K1: deg+rank histogram (0..241) || MFMA gemm + fused el/er ============
__global__ __launch_bounds__(256) void front_kernel(
    const float* __restrict__ feat, const float* __restrict__ W,
    const float* __restrict__ attn_l, const float* __restrict__ attn_r,
    const int* __restrict__ dst,
    unsigned short* __restrict__ feat_hd_bf,
    float* __restrict__ el, float* __restrict__ er,
    int* __restrict__ deg, int* __restrict__ rank) {
  __shared__ __align__(16) unsigned short sA[128 * LDT];   // 34816 B; reused as sOut
  __shared__ float sAttnL[128];
  __shared__ float sAttnR[128];
  const int bid = blockIdx.x;
  const int t = threadIdx.x;

  if (bid < DEG_BLOCKS) {
    // ---- degree histogram + rank capture, 8 atomics in flight ----
    for (int e0 = (bid * 256 + t) * 8; e0 < N_EDGES_C; e0 += DEG_BLOCKS * 2048) {
      int4 da = *(const int4*)&dst[e0];
      int4 db = *(const int4*)&dst[e0 + 4];
      int r0 = atomicAdd(&deg[da.x], 1);
      int r1 = atomicAdd(&deg[da.y], 1);
      int r2 = atomicAdd(&deg[da.z], 1);
      int r3 = atomicAdd(&deg[da.w], 1);
      int r4 = atomicAdd(&deg[db.x], 1);
      int r5 = atomicAdd(&deg[db.y], 1);
      int r6 = atomicAdd(&deg[db.z], 1);
      int r7 = atomicAdd(&deg[db.w], 1);
      *(int4*)&rank[e0]     = make_int4(r0, r1, r2, r3);
      *(int4*)&rank[e0 + 4] = make_int4(r4, r5, r6, r7);
    }
    return;
  }

  const int gb = bid - DEG_BLOCKS;
  const int nt = gb & 1;               // channel tile (heads nt*4 .. nt*4+3)
  const int mt = gb >> 1;
  const int m0 = mt * 128;
  const int n0 = nt * 128;

  if (t < 128) {
    sAttnL[t] = attn_l[n0 + t];
    sAttnR[t] = attn_r[n0 + t];
  }
  // stage A: 128 rows x 32 float4 of feat -> bf16 (nt load: feat is stream-once)
#pragma unroll
  for (int i = 0; i < 16; ++i) {
    int idx = t + i * 256;
    int row = idx >> 5;
    int c4 = idx & 31;
    int gn = m0 + row;
    floatx4 v = (floatx4){0.f, 0.f, 0.f, 0.f};
    if (gn < N_NODES_C)
      v = __builtin_nontemporal_load(
          (const floatx4*)&feat[(size_t)gn * IN_FEATS_C + c4 * 4]);
    ushort4 b;
    b.x = f2bf(v[0]); b.y = f2bf(v[1]); b.z = f2bf(v[2]); b.w = f2bf(v[3]);
    *(ushort4*)&sA[row * LDT + c4 * 4] = b;
  }
  __syncthreads();

  const int wid = t >> 6;
  const int lane = t & 63;
  const int quad = lane >> 4;
  const int l16 = lane & 15;
  const int wm = (wid & 1) * 64;
  const int wn = (wid >> 1) * 64;

  floatx4 acc[4][4];
#pragma unroll
  for (int i = 0; i < 4; ++i)
#pragma unroll
    for (int j = 0; j < 4; ++j) acc[i][j] = (floatx4){0.f, 0.f, 0.f, 0.f};

#pragma unroll
  for (int ks = 0; ks < 4; ++ks) {
    int k0 = ks * 32 + quad * 8;
    bf16x8 bfv[4];
#pragma unroll
    for (int n2 = 0; n2 < 4; ++n2) {
      const float* wp = &W[(size_t)(n0 + wn + n2 * 16 + l16) * IN_FEATS_C + k0];
      float4 w0 = *(const float4*)wp;
      float4 w1 = *(const float4*)(wp + 4);
      bf16x8 b;
      b[0] = (short)f2bf(w0.x); b[1] = (short)f2bf(w0.y);
      b[2] = (short)f2bf(w0.z); b[3] = (short)f2bf(w0.w);
      b[4] = (short)f2bf(w1.x); b[5] = (short)f2bf(w1.y);
      b[6] = (short)f2bf(w1.z); b[7] = (short)f2bf(w1.w);
      bfv[n2] = b;
    }
    bf16x8 af[4];
#pragma unroll
    for (int m2 = 0; m2 < 4; ++m2)
      af[m2] = *(const bf16x8*)&sA[(wm + m2 * 16 + l16) * LDT + k0];
#pragma unroll
    for (int m2 = 0; m2 < 4; ++m2)
#pragma unroll
      for (int n2 = 0; n2 < 4; ++n2)
        acc[m2][n2] = __builtin_amdgcn_mfma_f32_16x16x32_bf16(
            af[m2], bfv[n2], acc[m2][n2], 0, 0, 0);
  }
  __syncthreads();

  // epilogue: D layout col=l16, row=quad*4+reg -> repack via LDS
#pragma unroll
  for (int m2 = 0; m2 < 4; ++m2)
#pragma unroll
    for (int n2 = 0; n2 < 4; ++n2)
#pragma unroll
      for (int r = 0; r < 4; ++r) {
        int row = wm + m2 * 16 + quad * 4 + r;
        int col = wn + n2 * 16 + l16;
        sA[row * LDT + col] = f2bf(acc[m2][n2][r]);
      }
  __syncthreads();

  // coalesced store of the bf16 tile (plain store: round-2 known-good)
#pragma unroll
  for (int i = 0; i < 8; ++i) {
    int idx = t + i * 256;
    int row = idx >> 4;
    int ch = idx & 15;
    int gn = m0 + row;
    if (gn < N_NODES_C) {
      *(uint4*)&feat_hd_bf[(size_t)gn * HD_C + n0 + ch * 8] =
          *(const uint4*)&sA[row * LDT + ch * 8];
    }
  }

  // fused el/er: thread t -> row t>>1, head-pair t&1 (2 heads x 32 ch)
  {
    int row = t >> 1;
    int hh = t & 1;
    int gn = m0 + row;
    if (gn < N_NODES_C) {
      const unsigned short* pr = &sA[row * LDT + hh * 64];
      const float* al = &sAttnL[hh * 64];
      const float* ar = &sAttnR[hh * 64];
      float el0 = 0.f, el1 = 0.f, er0 = 0.f, er1 = 0.f;
#pragma unroll
      for (int d = 0; d < 32; ++d) {
        float v0 = bf2f(pr[d]);
        float v1 = bf2f(pr[32 + d]);
        el0 = fmaf(v0, al[d], el0);
        er0 = fmaf(v0, ar[d], er0);
        el1 = fmaf(v1, al[32 + d], el1);
        er1 = fmaf(v1, ar[32 + d], er1);
      }
      int gh = nt * 4 + hh * 2;
      el[gn * HEADS_C + gh + 0] = el0;
      el[gn * HEADS_C + gh + 1] = el1;
      er[gn * HEADS_C + gh + 0] = er0;
      er[gn * HEADS_C + gh + 1] = er1;
    }
  }
}

// ============ scan1: emits packed {row_start_incl, deg} int2 ============
__global__ __launch_bounds__(256) void scan1_kernel(
    const int* __restrict__ deg, int2* __restrict__ rsd,
    int* __restrict__ bsum) {
  __shared__ int s[256];
  int b = blockIdx.x, t = threadIdx.x;
  int i0 = b * 1024 + t * 4;
  int d0 = 0, d1 = 0, d2 = 0, d3 = 0;
  if (i0 + 4 <= N_NODES_C) {
    int4 d = *(const int4*)&deg[i0];
    d0 = d.x; d1 = d.y; d2 = d.z; d3 = d.w;
  } else {
    if (i0 + 0 < N_NODES_C) d0 = deg[i0 + 0];
    if (i0 + 1 < N_NODES_C) d1 = deg[i0 + 1];
    if (i0 + 2 < N_NODES_C) d2 = deg[i0 + 2];
    if (i0 + 3 < N_NODES_C) d3 = deg[i0 + 3];
  }
  int l1 = d0, l2 = l1 + d1, l3 = l2 + d2, l4 = l3 + d3;
  s[t] = l4;
  __syncthreads();
#pragma unroll
  for (int off = 1; off < 256; off <<= 1) {
    int add = (t >= off) ? s[t - off] : 0;
    __syncthreads();
    s[t] += add;
    __syncthreads();
  }
  int excl = s[t] - l4;
  if (i0 + 0 < N_NODES_C) rsd[i0 + 0] = make_int2(excl + l1, d0);
  if (i0 + 1 < N_NODES_C) rsd[i0 + 1] = make_int2(excl + l2, d1);
  if (i0 + 2 < N_NODES_C) rsd[i0 + 2] = make_int2(excl + l3, d2);
  if (i0 + 3 < N_NODES_C) rsd[i0 + 3] = make_int2(excl + l4, d3);
  if (t == 255) bsum[b] = s[255];
}

// ============ scatter: atomic-free, absolute CSR position from captured rank ============
__global__ __launch_bounds__(256) void scatter_kernel(
    const int* __restrict__ src, const int* __restrict__ dst,
    const int2* __restrict__ rsd, const int* __restrict__ bsum,
    const int* __restrict__ rank, int* __restrict__ csr_src) {
  __shared__ int sboff[64];
  boff_scan(bsum, sboff);
  int e = blockIdx.x * 256 + threadIdx.x;
  if (e >= N_EDGES_C) return;
  int d = dst[e];
  int2 v = rsd[d];                       // one 8B gather instead of two 4B
  int pos = v.x - v.y + sboff[d >> 10] + rank[e];
  csr_src[pos] = src[e];
}

// ============ aggregation: wave handles TWO independent nodes ============
// Round-2 per-node structure (known-good 69 µs) kept intact; the second,
// fully independent node stream doubles outstanding gathers per wave
// (~16 feat + 2 el + 2 idx) without any intra-stream dependency chain the
// compiler could serialize (round-3 failure mode). Done/empty streams clamp
// their index loads (L1-hot) and mask weights to 0.
__global__ __launch_bounds__(256) void agg_csr_kernel(
    const unsigned short* __restrict__ feat_hd_bf, const float* __restrict__ el,
    const float* __restrict__ er, const int2* __restrict__ rsd,
    const int* __restrict__ bsum, const int* __restrict__ csr_src,
    float* __restrict__ out) {
  __shared__ int sboff[64];
  boff_scan(bsum, sboff);
  int wvid = (blockIdx.x * 256 + threadIdx.x) >> 6;
  int lane = threadIdx.x & 63;
  int nodeA = wvid * 2;
  int nodeB = nodeA + 1;
  if (nodeA >= N_NODES_C) return;
  const bool hasB = (nodeB < N_NODES_C);
  int h = lane >> 3;
  int j8 = lane & 7;
  int hbase = lane & 56;               // h*8
  int c = lane * 4;

  int2 va = rsd[nodeA];
  int dgA = va.y;
  int rsA = va.x - dgA + sboff[nodeA >> 10];
  float erA = er[nodeA * HEADS_C + h];
  int dgB = 0, rsB = 0;
  float erB = 0.f;
  if (hasB) {
    int2 vb = rsd[nodeB];
    dgB = vb.y;
    rsB = vb.x - dgB + sboff[nodeB >> 10];
    erB = er[nodeB * HEADS_C + h];
  }

  float4 accA = make_float4(0.f, 0.f, 0.f, 0.f);
  float4 accB = make_float4(0.f, 0.f, 0.f, 0.f);
  float zA = 0.f, zB = 0.f;

  int nbA = (dgA + 7) >> 3;
  int nbB = (dgB + 7) >> 3;
  int nb = max(nbA, nbB);
  if (nb > 0) {
    const int lastA = (dgA > 0) ? dgA - 1 : 0;
    const int lastB = (dgB > 0) ? dgB - 1 : 0;
    int idxA = csr_src[min(rsA + min(j8, lastA), EMAX)];
    int idxB = csr_src[min(rsB + min(j8, lastB), EMAX)];
    for (int b = 0; b < nb; ++b) {
      int e0 = b * 8;
      // 16 independent feat gathers (two streams)
      ushort4 fa[8], fb[8];
#pragma unroll
      for (int j = 0; j < 8; ++j) {
        int sj = __shfl(idxA, j);
        fa[j] = *(const ushort4*)&feat_hd_bf[(size_t)sj * HD_C + c];
      }
#pragma unroll
      for (int j = 0; j < 8; ++j) {
        int sj = __shfl(idxB, j);
        fb[j] = *(const ushort4*)&feat_hd_bf[(size_t)sj * HD_C + c];
      }
      // per-lane edge weights (masked past segment end / for absent B)
      float xA = el[idxA * HEADS_C + h] + erA;
      xA = xA > 0.f ? xA : NEG_SLOPE_C * xA;
      float wvA = (e0 + j8 < dgA) ? __expf(xA) : 0.f;
      float xB = el[idxB * HEADS_C + h] + erB;
      xB = xB > 0.f ? xB : NEG_SLOPE_C * xB;
      float wvB = (e0 + j8 < dgB) ? __expf(xB) : 0.f;
      // prefetch next block's indices (clamped, branchless)
      int nidxA = csr_src[min(rsA + min(e0 + 8 + j8, lastA), EMAX)];
      int nidxB = csr_src[min(rsB + min(e0 + 8 + j8, lastB), EMAX)];
      // broadcast per-head weights and accumulate
      float wjA[8], wjB[8];
#pragma unroll
      for (int j = 0; j < 8; ++j) wjA[j] = __shfl(wvA, hbase + j);
#pragma unroll
      for (int j = 0; j < 8; ++j) wjB[j] = __shfl(wvB, hbase + j);
      zA += ((wjA[0] + wjA[1]) + (wjA[2] + wjA[3])) +
            ((wjA[4] + wjA[5]) + (wjA[6] + wjA[7]));
      zB += ((wjB[0] + wjB[1]) + (wjB[2] + wjB[3])) +
            ((wjB[4] + wjB[5]) + (wjB[6] + wjB[7]));
#pragma unroll
      for (int j = 0; j < 8; ++j) {
        accA.x = fmaf(wjA[j], bf2f(fa[j].x), accA.x);
        accA.y = fmaf(wjA[j], bf2f(fa[j].y), accA.y);
        accA.z = fmaf(wjA[j], bf2f(fa[j].z), accA.z);
        accA.w = fmaf(wjA[j], bf2f(fa[j].w), accA.w);
      }
#pragma unroll
      for (int j = 0; j < 8; ++j) {
        accB.x = fmaf(wjB[j], bf2f(fb[j].x), accB.x);
        accB.y = fmaf(wjB[j], bf2f(fb[j].y), accB.y);
        accB.z = fmaf(wjB[j], bf2f(fb[j].z), accB.z);
        accB.w = fmaf(wjB[j], bf2f(fb[j].w), accB.w);
      }
      idxA = nidxA;
      idxB = nidxB;
    }
  }

  float invA = (dgA > 0) ? 1.f / zA : 0.f;
  *(float4*)&out[(size_t)nodeA * HD_C + c] =
      make_float4(accA.x * invA, accA.y * invA, accA.z * invA, accA.w * invA);
  if (hasB) {
    float invB = (dgB > 0) ? 1.f / zB : 0.f;
    *(float4*)&out[(size_t)nodeB * HD_C + c] =
        make_float4(accB.x * invB, accB.y * invB, accB.z * invB, accB.w * invB);
  }
}

extern "C" void kernel_launch(void* const* d_in, const int* in_sizes, int n_in,
                              void* d_out, int out_size, void* d_ws, size_t ws_size,
                              hipStream_t stream) {
  const float* feat   = (const float*)d_in[0];
  const float* W      = (const float*)d_in[1];
  const float* attn_l = (const float*)d_in[2];
  const float* attn_r = (const float*)d_in[3];
  const int* src      = (const int*)d_in[4];
  const int* dst      = (const int*)d_in[5];
  float* out = (float*)d_out;

  char* ws = (char*)d_ws;
  unsigned short* feat_hd_bf = (unsigned short*)ws;  ws += (size_t)N_NODES_C * HD_C * 2;     // 25.6 MB
  float* el      = (float*)ws;                       ws += (size_t)N_NODES_C * HEADS_C * 4;  // 1.6 MB
  float* er      = (float*)ws;                       ws += (size_t)N_NODES_C * HEADS_C * 4;  // 1.6 MB
  int* deg       = (int*)ws;                         ws += (size_t)N_NODES_C * 4;
  int2* rsd      = (int2*)ws;                        ws += (size_t)N_NODES_C * 8;            // packed {row_start, deg}
  int* bsum      = (int*)ws;                         ws += 64 * 4;
  int* csr_src   = (int*)ws;                         ws += (size_t)N_EDGES_C * 4;            // 3.2 MB
  int* rank      = (int*)ws;                         ws += (size_t)N_EDGES_C * 4;            // 3.2 MB

  hipMemsetAsync(deg, 0, (size_t)N_NODES_C * 4, stream);

  front_kernel<<<K1_GRID, 256, 0, stream>>>(feat, W, attn_l, attn_r, dst,
                                            feat_hd_bf, el, er, deg, rank);

  scan1_kernel<<<SCAN_NBLK, 256, 0, stream>>>(deg, rsd, bsum);

  scatter_kernel<<<(N_EDGES_C + 255) / 256, 256, 0, stream>>>(
      src, dst, rsd, bsum, rank, csr_src);

  // 4 waves/block, 2 nodes/wave -> 8 nodes/block
  agg_csr_kernel<<<(N_NODES_C + 7) / 8, 256, 0, stream>>>(
      feat_hd_bf, el, er, rsd, bsum, csr_src, out);
}

// Round 5
// 222.414 us; speedup vs baseline: 1.1127x; 1.0449x over previous
//
#include <hip/hip_runtime.h>

#define N_NODES_C 50000
#define N_EDGES_C 800000
#define IN_FEATS_C 128
#define HEADS_C 8
#define HD_C 256            // HEADS * OUT_FEATS
#define NEG_SLOPE_C 0.2f
#define SCAN_NBLK 49        // ceil(50000/1024)
#define LDT 136             // LDS row stride in shorts (272 B = 17*16, 16B-aligned)

#define GEMM_BLOCKS 782     // ceil(50000/128) * 2 channel tiles
#define DEG_BLOCKS 242
#define K1_GRID (GEMM_BLOCKS + DEG_BLOCKS)   // 1024

typedef __attribute__((ext_vector_type(8))) short bf16x8;
typedef __attribute__((ext_vector_type(4))) float floatx4;

__device__ inline unsigned short f2bf(float f) {
  unsigned int u = __float_as_uint(f);
  unsigned int r = (u + 0x7FFFu + ((u >> 16) & 1u)) >> 16;   // RNE
  return (unsigned short)r;
}
__device__ inline float bf2f(unsigned short s) {
  unsigned int u = ((unsigned int)s) << 16;
  return __uint_as_float(u);
}

// 49-entry exclusive scan of bsum into sboff[64] (first wave only, then barrier)
__device__ inline void boff_scan(const int* __restrict__ bsum, int* sboff) {
  int t = threadIdx.x;
  if (t < 64) {
    int own = (t < SCAN_NBLK) ? bsum[t] : 0;
    int v = own;
#pragma unroll
    for (int off = 1; off < 64; off <<= 1) {
      int u = __shfl_up(v, off);
      if (t >= off) v += u;
    }
    sboff[t] = v - own;   // exclusive
  }
  __syncthreads();
}

// ============ wprep: one-time fp32 -> bf16 conversion of W ============
// Removes 391x redundant per-block W conversion from the GEMM inner loop.
__global__ __launch_bounds__(256) void wprep_kernel(
    const float* __restrict__ W, unsigned short* __restrict__ Wbf) {
  int i = (blockIdx.x * 256 + threadIdx.x) * 4;   // HD_C*IN_FEATS_C = 32768
  if (i < HD_C * IN_FEATS_C) {
    float4 v = *(const float4*)&W[i];
    ushort4 b;
    b.x = f2bf(v.x); b.y = f2bf(v.y); b.z = f2bf(v.z); b.w = f2bf(v.w);
    *(ushort4*)&Wbf[i] = b;
  }
}

// ============ K1: deg+rank histogram (0..241) || MFMA gemm + fused el/er ============
// GEMM block mapping pairs the two channel tiles of a row-block 8 bids apart:
// same XCD under round-robin dispatch and co-resident -> the twin's feat
// staging L2-hits instead of re-fetching 64 KB from HBM.
__global__ __launch_bounds__(256) void front_kernel(
    const float* __restrict__ feat, const unsigned short* __restrict__ Wbf,
    const float* __restrict__ attn_l, const float* __restrict__ attn_r,
    const int* __restrict__ dst,
    unsigned short* __restrict__ feat_hd_bf,
    float* __restrict__ el, float* __restrict__ er,
    int* __restrict__ deg, int* __restrict__ rank) {
  __shared__ __align__(16) unsigned short sA[128 * LDT];   // 34816 B; reused as sOut
  __shared__ float sAttnL[128];
  __shared__ float sAttnR[128];
  const int bid = blockIdx.x;
  const int t = threadIdx.x;

  if (bid < DEG_BLOCKS) {
    // ---- degree histogram + rank capture, 8 atomics in flight ----
    for (int e0 = (bid * 256 + t) * 8; e0 < N_EDGES_C; e0 += DEG_BLOCKS * 2048) {
      int4 da = *(const int4*)&dst[e0];
      int4 db = *(const int4*)&dst[e0 + 4];
      int r0 = atomicAdd(&deg[da.x], 1);
      int r1 = atomicAdd(&deg[da.y], 1);
      int r2 = atomicAdd(&deg[da.z], 1);
      int r3 = atomicAdd(&deg[da.w], 1);
      int r4 = atomicAdd(&deg[db.x], 1);
      int r5 = atomicAdd(&deg[db.y], 1);
      int r6 = atomicAdd(&deg[db.z], 1);
      int r7 = atomicAdd(&deg[db.w], 1);
      *(int4*)&rank[e0]     = make_int4(r0, r1, r2, r3);
      *(int4*)&rank[e0 + 4] = make_int4(r4, r5, r6, r7);
    }
    return;
  }

  const int gb = bid - DEG_BLOCKS;     // 0..781
  int mt, nt;
  if (gb < 768) {
    // groups of 16 bids cover 8 row-blocks x 2 channel tiles; twins differ by 8
    mt = ((gb >> 4) << 3) + (gb & 7);  // 0..383
    nt = (gb >> 3) & 1;
  } else {
    int l = gb - 768;                  // 0..13 -> row-blocks 384..390 x 2
    nt = (l >= 7) ? 1 : 0;
    mt = 384 + (nt ? l - 7 : l);
  }
  const int m0 = mt * 128;
  const int n0 = nt * 128;

  if (t < 128) {
    sAttnL[t] = attn_l[n0 + t];
    sAttnR[t] = attn_r[n0 + t];
  }
  // stage A: 128 rows x 32 float4 of feat -> bf16 (plain load: twin block L2-hits)
#pragma unroll
  for (int i = 0; i < 16; ++i) {
    int idx = t + i * 256;
    int row = idx >> 5;
    int c4 = idx & 31;
    int gn = m0 + row;
    float4 v = (gn < N_NODES_C)
                   ? *(const float4*)&feat[(size_t)gn * IN_FEATS_C + c4 * 4]
                   : make_float4(0.f, 0.f, 0.f, 0.f);
    ushort4 b;
    b.x = f2bf(v.x); b.y = f2bf(v.y); b.z = f2bf(v.z); b.w = f2bf(v.w);
    *(ushort4*)&sA[row * LDT + c4 * 4] = b;
  }
  __syncthreads();

  const int wid = t >> 6;
  const int lane = t & 63;
  const int quad = lane >> 4;
  const int l16 = lane & 15;
  const int wm = (wid & 1) * 64;
  const int wn = (wid >> 1) * 64;

  floatx4 acc[4][4];
#pragma unroll
  for (int i = 0; i < 4; ++i)
#pragma unroll
    for (int j = 0; j < 4; ++j) acc[i][j] = (floatx4){0.f, 0.f, 0.f, 0.f};

#pragma unroll
  for (int ks = 0; ks < 4; ++ks) {
    int k0 = ks * 32 + quad * 8;
    bf16x8 bfv[4];
#pragma unroll
    for (int n2 = 0; n2 < 4; ++n2)
      bfv[n2] = *(const bf16x8*)&Wbf[(size_t)(n0 + wn + n2 * 16 + l16) *
                                         IN_FEATS_C + k0];
    bf16x8 af[4];
#pragma unroll
    for (int m2 = 0; m2 < 4; ++m2)
      af[m2] = *(const bf16x8*)&sA[(wm + m2 * 16 + l16) * LDT + k0];
#pragma unroll
    for (int m2 = 0; m2 < 4; ++m2)
#pragma unroll
      for (int n2 = 0; n2 < 4; ++n2)
        acc[m2][n2] = __builtin_amdgcn_mfma_f32_16x16x32_bf16(
            af[m2], bfv[n2], acc[m2][n2], 0, 0, 0);
  }
  __syncthreads();

  // epilogue: D layout col=l16, row=quad*4+reg -> repack via LDS
#pragma unroll
  for (int m2 = 0; m2 < 4; ++m2)
#pragma unroll
    for (int n2 = 0; n2 < 4; ++n2)
#pragma unroll
      for (int r = 0; r < 4; ++r) {
        int row = wm + m2 * 16 + quad * 4 + r;
        int col = wn + n2 * 16 + l16;
        sA[row * LDT + col] = f2bf(acc[m2][n2][r]);
      }
  __syncthreads();

  // coalesced store of the bf16 tile
#pragma unroll
  for (int i = 0; i < 8; ++i) {
    int idx = t + i * 256;
    int row = idx >> 4;
    int ch = idx & 15;
    int gn = m0 + row;
    if (gn < N_NODES_C) {
      *(uint4*)&feat_hd_bf[(size_t)gn * HD_C + n0 + ch * 8] =
          *(const uint4*)&sA[row * LDT + ch * 8];
    }
  }

  // fused el/er: thread t -> row t>>1, head-pair t&1 (2 heads x 32 ch)
  {
    int row = t >> 1;
    int hh = t & 1;
    int gn = m0 + row;
    if (gn < N_NODES_C) {
      const unsigned short* pr = &sA[row * LDT + hh * 64];
      const float* al = &sAttnL[hh * 64];
      const float* ar = &sAttnR[hh * 64];
      float el0 = 0.f, el1 = 0.f, er0 = 0.f, er1 = 0.f;
#pragma unroll
      for (int d = 0; d < 32; ++d) {
        float v0 = bf2f(pr[d]);
        float v1 = bf2f(pr[32 + d]);
        el0 = fmaf(v0, al[d], el0);
        er0 = fmaf(v0, ar[d], er0);
        el1 = fmaf(v1, al[32 + d], el1);
        er1 = fmaf(v1, ar[32 + d], er1);
      }
      int gh = nt * 4 + hh * 2;
      el[gn * HEADS_C + gh + 0] = el0;
      el[gn * HEADS_C + gh + 1] = el1;
      er[gn * HEADS_C + gh + 0] = er0;
      er[gn * HEADS_C + gh + 1] = er1;
    }
  }
}

// ============ scan1: emits packed {row_start_incl, deg} int2 ============
__global__ __launch_bounds__(256) void scan1_kernel(
    const int* __restrict__ deg, int2* __restrict__ rsd,
    int* __restrict__ bsum) {
  __shared__ int s[256];
  int b = blockIdx.x, t = threadIdx.x;
  int i0 = b * 1024 + t * 4;
  int d0 = 0, d1 = 0, d2 = 0, d3 = 0;
  if (i0 + 4 <= N_NODES_C) {
    int4 d = *(const int4*)&deg[i0];
    d0 = d.x; d1 = d.y; d2 = d.z; d3 = d.w;
  } else {
    if (i0 + 0 < N_NODES_C) d0 = deg[i0 + 0];
    if (i0 + 1 < N_NODES_C) d1 = deg[i0 + 1];
    if (i0 + 2 < N_NODES_C) d2 = deg[i0 + 2];
    if (i0 + 3 < N_NODES_C) d3 = deg[i0 + 3];
  }
  int l1 = d0, l2 = l1 + d1, l3 = l2 + d2, l4 = l3 + d3;
  s[t] = l4;
  __syncthreads();
#pragma unroll
  for (int off = 1; off < 256; off <<= 1) {
    int add = (t >= off) ? s[t - off] : 0;
    __syncthreads();
    s[t] += add;
    __syncthreads();
  }
  int excl = s[t] - l4;
  if (i0 + 0 < N_NODES_C) rsd[i0 + 0] = make_int2(excl + l1, d0);
  if (i0 + 1 < N_NODES_C) rsd[i0 + 1] = make_int2(excl + l2, d1);
  if (i0 + 2 < N_NODES_C) rsd[i0 + 2] = make_int2(excl + l3, d2);
  if (i0 + 3 < N_NODES_C) rsd[i0 + 3] = make_int2(excl + l4, d3);
  if (t == 255) bsum[b] = s[255];
}

// ============ scatter: atomic-free, absolute CSR position from captured rank ============
__global__ __launch_bounds__(256) void scatter_kernel(
    const int* __restrict__ src, const int* __restrict__ dst,
    const int2* __restrict__ rsd, const int* __restrict__ bsum,
    const int* __restrict__ rank, int* __restrict__ csr_src) {
  __shared__ int sboff[64];
  boff_scan(bsum, sboff);
  int e = blockIdx.x * 256 + threadIdx.x;
  if (e >= N_EDGES_C) return;
  int d = dst[e];
  int2 v = rsd[d];                       // one 8B gather instead of two 4B
  int pos = v.x - v.y + sboff[d >> 10] + rank[e];
  csr_src[pos] = src[e];
}

// ============ aggregation over CSR: wave per dst node (round-2 structure) ============
// 8-edge blocks: one per-lane index load + shfl broadcast, next-block index
// prefetch overlapped with FMA, masked final block. Known-good 69.4 us.
__global__ __launch_bounds__(256) void agg_csr_kernel(
    const unsigned short* __restrict__ feat_hd_bf, const float* __restrict__ el,
    const float* __restrict__ er, const int2* __restrict__ rsd,
    const int* __restrict__ bsum, const int* __restrict__ csr_src,
    float* __restrict__ out) {
  __shared__ int sboff[64];
  boff_scan(bsum, sboff);
  int gid = blockIdx.x * 256 + threadIdx.x;
  int node = gid >> 6;
  int lane = threadIdx.x & 63;
  if (node >= N_NODES_C) return;
  int h = lane >> 3;
  int j8 = lane & 7;
  int hbase = lane & 56;               // h*8
  int c = lane * 4;
  float er_d = er[node * HEADS_C + h];
  int2 v = rsd[node];
  int dg = v.y;
  int rs = v.x - dg + sboff[node >> 10];
  float4 acc = make_float4(0.f, 0.f, 0.f, 0.f);
  float zsum = 0.f;

  int nb = (dg + 7) >> 3;              // number of 8-edge blocks (masked tail)
  if (nb > 0) {
    const int last = dg - 1;
    int myidx = csr_src[rs + min(j8, last)];
    for (int b = 0; b < nb; ++b) {
      int e0 = b * 8;
      ushort4 f[8];
#pragma unroll
      for (int j = 0; j < 8; ++j) {
        int sj = __shfl(myidx, j);
        f[j] = *(const ushort4*)&feat_hd_bf[(size_t)sj * HD_C + c];
      }
      float x = el[myidx * HEADS_C + h] + er_d;
      x = x > 0.f ? x : NEG_SLOPE_C * x;
      float wv = (e0 + j8 < dg) ? __expf(x) : 0.f;
      int nidx = csr_src[rs + min(e0 + 8 + j8, last)];
      float wj[8];
#pragma unroll
      for (int j = 0; j < 8; ++j) wj[j] = __shfl(wv, hbase + j);
      zsum += ((wj[0] + wj[1]) + (wj[2] + wj[3])) +
              ((wj[4] + wj[5]) + (wj[6] + wj[7]));
#pragma unroll
      for (int j = 0; j < 8; ++j) {
        acc.x = fmaf(wj[j], bf2f(f[j].x), acc.x);
        acc.y = fmaf(wj[j], bf2f(f[j].y), acc.y);
        acc.z = fmaf(wj[j], bf2f(f[j].z), acc.z);
        acc.w = fmaf(wj[j], bf2f(f[j].w), acc.w);
      }
      myidx = nidx;
    }
  }

  float inv = (dg > 0) ? 1.f / zsum : 0.f;
  acc.x *= inv; acc.y *= inv; acc.z *= inv; acc.w *= inv;
  *(float4*)&out[(size_t)node * HD_C + c] = acc;
}

extern "C" void kernel_launch(void* const* d_in, const int* in_sizes, int n_in,
                              void* d_out, int out_size, void* d_ws, size_t ws_size,
                              hipStream_t stream) {
  const float* feat   = (const float*)d_in[0];
  const float* W      = (const float*)d_in[1];
  const float* attn_l = (const float*)d_in[2];
  const float* attn_r = (const float*)d_in[3];
  const int* src      = (const int*)d_in[4];
  const int* dst      = (const int*)d_in[5];
  float* out = (float*)d_out;

  char* ws = (char*)d_ws;
  unsigned short* feat_hd_bf = (unsigned short*)ws;  ws += (size_t)N_NODES_C * HD_C * 2;     // 25.6 MB
  float* el      = (float*)ws;                       ws += (size_t)N_NODES_C * HEADS_C * 4;  // 1.6 MB
  float* er      = (float*)ws;                       ws += (size_t)N_NODES_C * HEADS_C * 4;  // 1.6 MB
  int* deg       = (int*)ws;                         ws += (size_t)N_NODES_C * 4;
  int2* rsd      = (int2*)ws;                        ws += (size_t)N_NODES_C * 8;            // packed {row_start, deg}
  int* bsum      = (int*)ws;                         ws += 64 * 4;
  int* csr_src   = (int*)ws;                         ws += (size_t)N_EDGES_C * 4;            // 3.2 MB
  int* rank      = (int*)ws;                         ws += (size_t)N_EDGES_C * 4;            // 3.2 MB
  unsigned short* Wbf = (unsigned short*)ws;         ws += (size_t)HD_C * IN_FEATS_C * 2;    // 64 KB

  hipMemsetAsync(deg, 0, (size_t)N_NODES_C * 4, stream);

  wprep_kernel<<<(HD_C * IN_FEATS_C) / 1024, 256, 0, stream>>>(W, Wbf);

  front_kernel<<<K1_GRID, 256, 0, stream>>>(feat, Wbf, attn_l, attn_r, dst,
                                            feat_hd_bf, el, er, deg, rank);

  scan1_kernel<<<SCAN_NBLK, 256, 0, stream>>>(deg, rsd, bsum);

  scatter_kernel<<<(N_EDGES_C + 255) / 256, 256, 0, stream>>>(
      src, dst, rsd, bsum, rank, csr_src);

  agg_csr_kernel<<<(N_NODES_C + 3) / 4, 256, 0, stream>>>(
      feat_hd_bf, el, er, rsd, bsum, csr_src, out);
}

// Round 6
// 221.295 us; speedup vs baseline: 1.1183x; 1.0051x over previous
//
#include <hip/hip_runtime.h>

#define N_NODES_C 50000
#define N_EDGES_C 800000
#define IN_FEATS_C 128
#define HEADS_C 8
#define HD_C 256            // HEADS * OUT_FEATS
#define NEG_SLOPE_C 0.2f
#define SCAN_NBLK 49        // ceil(50000/1024)
#define LDT 136             // LDS row stride in shorts (272 B = 17*16, 16B-aligned)

#define GEMM_BLOCKS 782     // ceil(50000/128) * 2 channel tiles
#define DEG_BLOCKS 242
#define K1_GRID (GEMM_BLOCKS + DEG_BLOCKS)   // 1024

typedef __attribute__((ext_vector_type(8))) short bf16x8;
typedef __attribute__((ext_vector_type(4))) float floatx4;

__device__ inline unsigned short f2bf(float f) {
  unsigned int u = __float_as_uint(f);
  unsigned int r = (u + 0x7FFFu + ((u >> 16) & 1u)) >> 16;   // RNE
  return (unsigned short)r;
}
__device__ inline float bf2f(unsigned short s) {
  unsigned int u = ((unsigned int)s) << 16;
  return __uint_as_float(u);
}

// 49-entry exclusive scan of bsum into sboff[64] (first wave only, then barrier)
__device__ inline void boff_scan(const int* __restrict__ bsum, int* sboff) {
  int t = threadIdx.x;
  if (t < 64) {
    int own = (t < SCAN_NBLK) ? bsum[t] : 0;
    int v = own;
#pragma unroll
    for (int off = 1; off < 64; off <<= 1) {
      int u = __shfl_up(v, off);
      if (t >= off) v += u;
    }
    sboff[t] = v - own;   // exclusive
  }
  __syncthreads();
}

// ============ prep: fused {W fp32->bf16 conversion, deg zeroing} ============
// blocks 0..31: convert W (32768 floats). blocks 32..80: zero deg (50000 ints).
__global__ __launch_bounds__(256) void prep_kernel(
    const float* __restrict__ W, unsigned short* __restrict__ Wbf,
    int* __restrict__ deg) {
  int b = blockIdx.x, t = threadIdx.x;
  if (b < 32) {
    int i = (b * 256 + t) * 4;
    float4 v = *(const float4*)&W[i];
    ushort4 o;
    o.x = f2bf(v.x); o.y = f2bf(v.y); o.z = f2bf(v.z); o.w = f2bf(v.w);
    *(ushort4*)&Wbf[i] = o;
  } else {
    int i = ((b - 32) * 256 + t) * 4;
    if (i < N_NODES_C) {
      if (i + 4 <= N_NODES_C)
        *(int4*)&deg[i] = make_int4(0, 0, 0, 0);
      else
        for (int k = i; k < N_NODES_C; ++k) deg[k] = 0;
    }
  }
}

// ============ K1: deg+rank histogram (0..241) || MFMA gemm + fused el/er ============
// GEMM block mapping pairs the two channel tiles of a row-block 8 bids apart:
// same XCD under round-robin dispatch and co-resident -> the twin's feat
// staging L2-hits instead of re-fetching 64 KB from HBM.
__global__ __launch_bounds__(256) void front_kernel(
    const float* __restrict__ feat, const unsigned short* __restrict__ Wbf,
    const float* __restrict__ attn_l, const float* __restrict__ attn_r,
    const int* __restrict__ dst,
    unsigned short* __restrict__ feat_hd_bf,
    float* __restrict__ el, float* __restrict__ er,
    int* __restrict__ deg, int* __restrict__ rank) {
  __shared__ __align__(16) unsigned short sA[128 * LDT];   // 34816 B; reused as sOut
  __shared__ float sAttnL[128];
  __shared__ float sAttnR[128];
  const int bid = blockIdx.x;
  const int t = threadIdx.x;

  if (bid < DEG_BLOCKS) {
    // ---- degree histogram + rank capture, 8 atomics in flight ----
    for (int e0 = (bid * 256 + t) * 8; e0 < N_EDGES_C; e0 += DEG_BLOCKS * 2048) {
      int4 da = *(const int4*)&dst[e0];
      int4 db = *(const int4*)&dst[e0 + 4];
      int r0 = atomicAdd(&deg[da.x], 1);
      int r1 = atomicAdd(&deg[da.y], 1);
      int r2 = atomicAdd(&deg[da.z], 1);
      int r3 = atomicAdd(&deg[da.w], 1);
      int r4 = atomicAdd(&deg[db.x], 1);
      int r5 = atomicAdd(&deg[db.y], 1);
      int r6 = atomicAdd(&deg[db.z], 1);
      int r7 = atomicAdd(&deg[db.w], 1);
      *(int4*)&rank[e0]     = make_int4(r0, r1, r2, r3);
      *(int4*)&rank[e0 + 4] = make_int4(r4, r5, r6, r7);
    }
    return;
  }

  const int gb = bid - DEG_BLOCKS;     // 0..781
  int mt, nt;
  if (gb < 768) {
    // groups of 16 bids cover 8 row-blocks x 2 channel tiles; twins differ by 8
    mt = ((gb >> 4) << 3) + (gb & 7);  // 0..383
    nt = (gb >> 3) & 1;
  } else {
    int l = gb - 768;                  // 0..13 -> row-blocks 384..390 x 2
    nt = (l >= 7) ? 1 : 0;
    mt = 384 + (nt ? l - 7 : l);
  }
  const int m0 = mt * 128;
  const int n0 = nt * 128;

  if (t < 128) {
    sAttnL[t] = attn_l[n0 + t];
    sAttnR[t] = attn_r[n0 + t];
  }
  // stage A: 128 rows x 32 float4 of feat -> bf16 (plain load: twin block L2-hits)
#pragma unroll
  for (int i = 0; i < 16; ++i) {
    int idx = t + i * 256;
    int row = idx >> 5;
    int c4 = idx & 31;
    int gn = m0 + row;
    float4 v = (gn < N_NODES_C)
                   ? *(const float4*)&feat[(size_t)gn * IN_FEATS_C + c4 * 4]
                   : make_float4(0.f, 0.f, 0.f, 0.f);
    ushort4 b;
    b.x = f2bf(v.x); b.y = f2bf(v.y); b.z = f2bf(v.z); b.w = f2bf(v.w);
    *(ushort4*)&sA[row * LDT + c4 * 4] = b;
  }
  __syncthreads();

  const int wid = t >> 6;
  const int lane = t & 63;
  const int quad = lane >> 4;
  const int l16 = lane & 15;
  const int wm = (wid & 1) * 64;
  const int wn = (wid >> 1) * 64;

  floatx4 acc[4][4];
#pragma unroll
  for (int i = 0; i < 4; ++i)
#pragma unroll
    for (int j = 0; j < 4; ++j) acc[i][j] = (floatx4){0.f, 0.f, 0.f, 0.f};

#pragma unroll
  for (int ks = 0; ks < 4; ++ks) {
    int k0 = ks * 32 + quad * 8;
    bf16x8 bfv[4];
#pragma unroll
    for (int n2 = 0; n2 < 4; ++n2)
      bfv[n2] = *(const bf16x8*)&Wbf[(size_t)(n0 + wn + n2 * 16 + l16) *
                                         IN_FEATS_C + k0];
    bf16x8 af[4];
#pragma unroll
    for (int m2 = 0; m2 < 4; ++m2)
      af[m2] = *(const bf16x8*)&sA[(wm + m2 * 16 + l16) * LDT + k0];
#pragma unroll
    for (int m2 = 0; m2 < 4; ++m2)
#pragma unroll
      for (int n2 = 0; n2 < 4; ++n2)
        acc[m2][n2] = __builtin_amdgcn_mfma_f32_16x16x32_bf16(
            af[m2], bfv[n2], acc[m2][n2], 0, 0, 0);
  }
  __syncthreads();

  // epilogue: D layout col=l16, row=quad*4+reg -> repack via LDS
#pragma unroll
  for (int m2 = 0; m2 < 4; ++m2)
#pragma unroll
    for (int n2 = 0; n2 < 4; ++n2)
#pragma unroll
      for (int r = 0; r < 4; ++r) {
        int row = wm + m2 * 16 + quad * 4 + r;
        int col = wn + n2 * 16 + l16;
        sA[row * LDT + col] = f2bf(acc[m2][n2][r]);
      }
  __syncthreads();

  // coalesced store of the bf16 tile
#pragma unroll
  for (int i = 0; i < 8; ++i) {
    int idx = t + i * 256;
    int row = idx >> 4;
    int ch = idx & 15;
    int gn = m0 + row;
    if (gn < N_NODES_C) {
      *(uint4*)&feat_hd_bf[(size_t)gn * HD_C + n0 + ch * 8] =
          *(const uint4*)&sA[row * LDT + ch * 8];
    }
  }

  // fused el/er: thread t -> row t>>1, head-pair t&1 (2 heads x 32 ch)
  // vectorized b128 LDS reads (8x bf16x8) instead of 128 scalar ds_read_u16
  {
    int row = t >> 1;
    int hh = t & 1;
    int gn = m0 + row;
    if (gn < N_NODES_C) {
      const unsigned short* pr = &sA[row * LDT + hh * 64];
      const float* al = &sAttnL[hh * 64];
      const float* ar = &sAttnR[hh * 64];
      float el0 = 0.f, el1 = 0.f, er0 = 0.f, er1 = 0.f;
#pragma unroll
      for (int d8 = 0; d8 < 4; ++d8) {
        bf16x8 v0 = *(const bf16x8*)&pr[d8 * 8];        // head gh:   ch d8*8..+8
        bf16x8 v1 = *(const bf16x8*)&pr[32 + d8 * 8];   // head gh+1
#pragma unroll
        for (int j = 0; j < 8; ++j) {
          float f0 = bf2f((unsigned short)v0[j]);
          float f1 = bf2f((unsigned short)v1[j]);
          el0 = fmaf(f0, al[d8 * 8 + j], el0);
          er0 = fmaf(f0, ar[d8 * 8 + j], er0);
          el1 = fmaf(f1, al[32 + d8 * 8 + j], el1);
          er1 = fmaf(f1, ar[32 + d8 * 8 + j], er1);
        }
      }
      int gh = nt * 4 + hh * 2;
      el[gn * HEADS_C + gh + 0] = el0;
      el[gn * HEADS_C + gh + 1] = el1;
      er[gn * HEADS_C + gh + 0] = er0;
      er[gn * HEADS_C + gh + 1] = er1;
    }
  }
}

// ============ scan1: emits packed {row_start_incl, deg} int2 ============
__global__ __launch_bounds__(256) void scan1_kernel(
    const int* __restrict__ deg, int2* __restrict__ rsd,
    int* __restrict__ bsum) {
  __shared__ int s[256];
  int b = blockIdx.x, t = threadIdx.x;
  int i0 = b * 1024 + t * 4;
  int d0 = 0, d1 = 0, d2 = 0, d3 = 0;
  if (i0 + 4 <= N_NODES_C) {
    int4 d = *(const int4*)&deg[i0];
    d0 = d.x; d1 = d.y; d2 = d.z; d3 = d.w;
  } else {
    if (i0 + 0 < N_NODES_C) d0 = deg[i0 + 0];
    if (i0 + 1 < N_NODES_C) d1 = deg[i0 + 1];
    if (i0 + 2 < N_NODES_C) d2 = deg[i0 + 2];
    if (i0 + 3 < N_NODES_C) d3 = deg[i0 + 3];
  }
  int l1 = d0, l2 = l1 + d1, l3 = l2 + d2, l4 = l3 + d3;
  s[t] = l4;
  __syncthreads();
#pragma unroll
  for (int off = 1; off < 256; off <<= 1) {
    int add = (t >= off) ? s[t - off] : 0;
    __syncthreads();
    s[t] += add;
    __syncthreads();
  }
  int excl = s[t] - l4;
  if (i0 + 0 < N_NODES_C) rsd[i0 + 0] = make_int2(excl + l1, d0);
  if (i0 + 1 < N_NODES_C) rsd[i0 + 1] = make_int2(excl + l2, d1);
  if (i0 + 2 < N_NODES_C) rsd[i0 + 2] = make_int2(excl + l3, d2);
  if (i0 + 3 < N_NODES_C) rsd[i0 + 3] = make_int2(excl + l4, d3);
  if (t == 255) bsum[b] = s[255];
}

// ============ scatter: atomic-free, 4 edges/thread for MLP ============
// int4 loads of dst/rank/src, 4 independent rsd gathers and 4 independent
// scattered stores in flight per thread (was 1 serialized chain per thread).
__global__ __launch_bounds__(256) void scatter_kernel(
    const int* __restrict__ src, const int* __restrict__ dst,
    const int2* __restrict__ rsd, const int* __restrict__ bsum,
    const int* __restrict__ rank, int* __restrict__ csr_src) {
  __shared__ int sboff[64];
  boff_scan(bsum, sboff);
  int base = (blockIdx.x * 256 + threadIdx.x) * 4;
  if (base >= N_EDGES_C) return;           // N_EDGES_C % 4 == 0 -> full int4
  int4 d4 = *(const int4*)&dst[base];
  int4 r4 = *(const int4*)&rank[base];
  int4 s4 = *(const int4*)&src[base];
  int2 v0 = rsd[d4.x];
  int2 v1 = rsd[d4.y];
  int2 v2 = rsd[d4.z];
  int2 v3 = rsd[d4.w];
  csr_src[v0.x - v0.y + sboff[d4.x >> 10] + r4.x] = s4.x;
  csr_src[v1.x - v1.y + sboff[d4.y >> 10] + r4.y] = s4.y;
  csr_src[v2.x - v2.y + sboff[d4.z >> 10] + r4.z] = s4.z;
  csr_src[v3.x - v3.y + sboff[d4.w >> 10] + r4.w] = s4.w;
}

// ============ aggregation over CSR: wave per dst node (round-2 structure) ============
// 8-edge blocks: one per-lane index load + shfl broadcast, next-block index
// prefetch overlapped with FMA, masked final block. At its structural floor
// (~69.5 us, ~211 MB fetch @ ~3.9 TB/s random-gather rate) - do not touch.
__global__ __launch_bounds__(256) void agg_csr_kernel(
    const unsigned short* __restrict__ feat_hd_bf, const float* __restrict__ el,
    const float* __restrict__ er, const int2* __restrict__ rsd,
    const int* __restrict__ bsum, const int* __restrict__ csr_src,
    float* __restrict__ out) {
  __shared__ int sboff[64];
  boff_scan(bsum, sboff);
  int gid = blockIdx.x * 256 + threadIdx.x;
  int node = gid >> 6;
  int lane = threadIdx.x & 63;
  if (node >= N_NODES_C) return;
  int h = lane >> 3;
  int j8 = lane & 7;
  int hbase = lane & 56;               // h*8
  int c = lane * 4;
  float er_d = er[node * HEADS_C + h];
  int2 v = rsd[node];
  int dg = v.y;
  int rs = v.x - dg + sboff[node >> 10];
  float4 acc = make_float4(0.f, 0.f, 0.f, 0.f);
  float zsum = 0.f;

  int nb = (dg + 7) >> 3;              // number of 8-edge blocks (masked tail)
  if (nb > 0) {
    const int last = dg - 1;
    int myidx = csr_src[rs + min(j8, last)];
    for (int b = 0; b < nb; ++b) {
      int e0 = b * 8;
      ushort4 f[8];
#pragma unroll
      for (int j = 0; j < 8; ++j) {
        int sj = __shfl(myidx, j);
        f[j] = *(const ushort4*)&feat_hd_bf[(size_t)sj * HD_C + c];
      }
      float x = el[myidx * HEADS_C + h] + er_d;
      x = x > 0.f ? x : NEG_SLOPE_C * x;
      float wv = (e0 + j8 < dg) ? __expf(x) : 0.f;
      int nidx = csr_src[rs + min(e0 + 8 + j8, last)];
      float wj[8];
#pragma unroll
      for (int j = 0; j < 8; ++j) wj[j] = __shfl(wv, hbase + j);
      zsum += ((wj[0] + wj[1]) + (wj[2] + wj[3])) +
              ((wj[4] + wj[5]) + (wj[6] + wj[7]));
#pragma unroll
      for (int j = 0; j < 8; ++j) {
        acc.x = fmaf(wj[j], bf2f(f[j].x), acc.x);
        acc.y = fmaf(wj[j], bf2f(f[j].y), acc.y);
        acc.z = fmaf(wj[j], bf2f(f[j].z), acc.z);
        acc.w = fmaf(wj[j], bf2f(f[j].w), acc.w);
      }
      myidx = nidx;
    }
  }

  float inv = (dg > 0) ? 1.f / zsum : 0.f;
  acc.x *= inv; acc.y *= inv; acc.z *= inv; acc.w *= inv;
  *(float4*)&out[(size_t)node * HD_C + c] = acc;
}

extern "C" void kernel_launch(void* const* d_in, const int* in_sizes, int n_in,
                              void* d_out, int out_size, void* d_ws, size_t ws_size,
                              hipStream_t stream) {
  const float* feat   = (const float*)d_in[0];
  const float* W      = (const float*)d_in[1];
  const float* attn_l = (const float*)d_in[2];
  const float* attn_r = (const float*)d_in[3];
  const int* src      = (const int*)d_in[4];
  const int* dst      = (const int*)d_in[5];
  float* out = (float*)d_out;

  char* ws = (char*)d_ws;
  unsigned short* feat_hd_bf = (unsigned short*)ws;  ws += (size_t)N_NODES_C * HD_C * 2;     // 25.6 MB
  float* el      = (float*)ws;                       ws += (size_t)N_NODES_C * HEADS_C * 4;  // 1.6 MB
  float* er      = (float*)ws;                       ws += (size_t)N_NODES_C * HEADS_C * 4;  // 1.6 MB
  int* deg       = (int*)ws;                         ws += (size_t)N_NODES_C * 4;
  int2* rsd      = (int2*)ws;                        ws += (size_t)N_NODES_C * 8;            // packed {row_start, deg}
  int* bsum      = (int*)ws;                         ws += 64 * 4;
  int* csr_src   = (int*)ws;                         ws += (size_t)N_EDGES_C * 4;            // 3.2 MB
  int* rank      = (int*)ws;                         ws += (size_t)N_EDGES_C * 4;            // 3.2 MB
  unsigned short* Wbf = (unsigned short*)ws;         ws += (size_t)HD_C * IN_FEATS_C * 2;    // 64 KB

  prep_kernel<<<81, 256, 0, stream>>>(W, Wbf, deg);

  front_kernel<<<K1_GRID, 256, 0, stream>>>(feat, Wbf, attn_l, attn_r, dst,
                                            feat_hd_bf, el, er, deg, rank);

  scan1_kernel<<<SCAN_NBLK, 256, 0, stream>>>(deg, rsd, bsum);

  scatter_kernel<<<(N_EDGES_C / 4 + 255) / 256, 256, 0, stream>>>(
      src, dst, rsd, bsum, rank, csr_src);

  agg_csr_kernel<<<(N_NODES_C + 3) / 4, 256, 0, stream>>>(
      feat_hd_bf, el, er, rsd, bsum, csr_src, out);
}